// Round 11
// baseline (544.080 us; speedup 1.0000x reference)
//
#include <hip/hip_runtime.h>
#include <cstdint>
#include <cstddef>

constexpr int N_  = 20480;
constexpr int E_  = 163840;
constexpr int G_  = 512;
constexpr int D_  = 128;
constexpr int H_  = 4;
constexpr int R_  = 8;
constexpr int L_  = 4;
constexpr int HK_ = 512;   // H*D
constexpr int NPG_ = N_ / G_; // 40

typedef short short8 __attribute__((ext_vector_type(8)));
typedef float f32x4 __attribute__((ext_vector_type(4)));
typedef unsigned short u16;
typedef unsigned int u32;

__device__ inline u16 bfr(float f) {  // fp32 -> bf16 RNE
  u32 u = __builtin_bit_cast(u32, f);
  return (u16)((u + 0x7fffu + ((u >> 16) & 1u)) >> 16);
}
__device__ inline float bf2f(u32 lo16) { return __builtin_bit_cast(float, lo16 << 16); }
__device__ inline float lrelu(float v) { return v >= 0.f ? v : 0.2f * v; }

// ---------------- zero helper ----------------
__global__ void k_zero_i(int* __restrict__ p, int n) {
  int i = blockIdx.x * blockDim.x + threadIdx.x;
  if (i < n) p[i] = 0;
}

// ---------------- CSR builds ----------------
__global__ void k_count_rel(const int* __restrict__ dst, const int* __restrict__ et,
                            int* __restrict__ counts) {
  int e = blockIdx.x * blockDim.x + threadIdx.x;
  if (e < E_) atomicAdd(&counts[et[e] * N_ + dst[e]], 1);
}
__global__ void k_count_dst(const int* __restrict__ dst, int* __restrict__ counts) {
  int e = blockIdx.x * blockDim.x + threadIdx.x;
  if (e < E_) atomicAdd(&counts[dst[e]], 1);
}
__global__ void k_bsum(const int* __restrict__ c, int* __restrict__ bsum) {
  int t = threadIdx.x;
  const int4 v = *(const int4*)&c[blockIdx.x * 1024 + t * 4];
  int s = v.x + v.y + v.z + v.w;
#pragma unroll
  for (int o = 32; o; o >>= 1) s += __shfl_down(s, o, 64);
  __shared__ int ws_[4];
  if ((t & 63) == 0) ws_[t >> 6] = s;
  __syncthreads();
  if (t == 0) bsum[blockIdx.x] = ws_[0] + ws_[1] + ws_[2] + ws_[3];
}
// writes grand total too (r6 lesson: indptr[last] MUST be initialized)
__global__ void k_bscan(int* __restrict__ bsum, int nb, int* __restrict__ tot_out) {
  __shared__ int sh[512];
  int t = threadIdx.x;
  if (t < nb) sh[t] = bsum[t];
  __syncthreads();
  if (t == 0) {
    int run = 0;
    for (int i = 0; i < nb; ++i) { int v = sh[i]; sh[i] = run; run += v; }
    tot_out[0] = run;
  }
  __syncthreads();
  if (t < nb) bsum[t] = sh[t];
}
__global__ void k_scan3(const int* __restrict__ c, const int* __restrict__ bsum,
                        int* __restrict__ indptr, int* __restrict__ cursor) {
  __shared__ int ts[256];
  int t = threadIdx.x;
  int base = blockIdx.x * 1024 + t * 4;
  const int4 v = *(const int4*)&c[base];
  int s0 = v.x, s01 = v.x + v.y, s012 = s01 + v.z, s = s012 + v.w;
  ts[t] = s;
  __syncthreads();
#pragma unroll
  for (int o = 1; o < 256; o <<= 1) {
    int add = (t >= o) ? ts[t - o] : 0;
    __syncthreads();
    ts[t] += add;
    __syncthreads();
  }
  int off = bsum[blockIdx.x] + (t ? ts[t - 1] : 0);
  int4 o4 = make_int4(off, off + s0, off + s01, off + s012);
  *(int4*)&indptr[base] = o4;
  *(int4*)&cursor[base] = o4;
}
// rel scatter; also records slotOf[e] and srcR[slot] (static per session)
__global__ void k_scatter_rel(const int* __restrict__ dst, const int* __restrict__ et,
                              const int* __restrict__ src, int* __restrict__ cursor,
                              int* __restrict__ esort, int* __restrict__ slotOf,
                              int* __restrict__ srcR) {
  int e = blockIdx.x * blockDim.x + threadIdx.x;
  if (e < E_) {
    int p = atomicAdd(&cursor[et[e] * N_ + dst[e]], 1);
    esort[p] = e;
    slotOf[e] = p;
    srcR[p] = src[e];
  }
}
__global__ void k_scatter_dst(const int* __restrict__ dst, int* __restrict__ cursor,
                              int* __restrict__ esort) {
  int e = blockIdx.x * blockDim.x + threadIdx.x;
  if (e < E_) {
    int p = atomicAdd(&cursor[dst[e]], 1);
    esort[p] = e;
  }
}
__global__ void k_padbase(const int* __restrict__ indptrR, int* __restrict__ padBase) {
  if (threadIdx.x == 0 && blockIdx.x == 0) {
    int cum = 0;
    for (int r = 0; r < R_; ++r) {
      padBase[r] = cum;
      int cnt = indptrR[(r + 1) * N_] - indptrR[r * N_];
      cum += (cnt + 63) & ~63;
    }
    padBase[R_] = cum;
  }
}

// ---------------- embedding lookup (writes fp32 + bf16) ----------------
__global__ void k_embed(const int* __restrict__ xn, const float* __restrict__ emb,
                        float* __restrict__ x, u16* __restrict__ xb) {
  int i = blockIdx.x * blockDim.x + threadIdx.x;
  if (i < N_ * D_) {
    int n = i >> 7, d = i & 127;
    float v = emb[xn[n] * D_ + d];
    x[i] = v;
    xb[i] = bfr(v);
  }
}

// ---------------- WQK for ALL layers: wave per (l,r,d) row ----------------
__global__ __launch_bounds__(256) void k_wqk_all(const float* __restrict__ W,
                                                 const float* __restrict__ Q,
                                                 const float* __restrict__ Km,
                                                 float* __restrict__ WQK) {
  int gw = (blockIdx.x * 256 + threadIdx.x) >> 6;  // 0..L*R*D-1 = 4095
  int lane = threadIdx.x & 63;
  int d = gw & 127, r = (gw >> 7) & 7, l = gw >> 10;
  const float* wrow = W + (((size_t)l * R_ + r) * D_ + d) * HK_;
  const float* Ql = Q + (size_t)l * HK_ * H_;
  const float* Kl = Km + (size_t)l * HK_ * H_;
  float acc[8] = {0.f, 0.f, 0.f, 0.f, 0.f, 0.f, 0.f, 0.f};
#pragma unroll
  for (int it = 0; it < 8; ++it) {
    int k = it * 64 + lane;
    float w = wrow[k];
    const float4 qv = *(const float4*)&Ql[k * 4];
    const float4 kv = *(const float4*)&Kl[k * 4];
    acc[0] += w * qv.x; acc[1] += w * qv.y; acc[2] += w * qv.z; acc[3] += w * qv.w;
    acc[4] += w * kv.x; acc[5] += w * kv.y; acc[6] += w * kv.z; acc[7] += w * kv.w;
  }
#pragma unroll
  for (int o = 32; o; o >>= 1)
#pragma unroll
    for (int j = 0; j < 8; ++j) acc[j] += __shfl_down(acc[j], o, 64);
  if (lane == 0) {
#pragma unroll
    for (int h = 0; h < 4; ++h) {
      WQK[((size_t)l * D_ + d) * 64 + r * 4 + h] = acc[h];
      WQK[((size_t)l * D_ + d) * 64 + 32 + r * 4 + h] = acc[4 + h];
    }
  }
}

// ---------------- q,k: LDS-tiled small GEMM (32 nodes/block) ----------------
__global__ __launch_bounds__(256) void k_qk(const float* __restrict__ x,
                                            const float* __restrict__ WQK,
                                            float* __restrict__ q,
                                            float* __restrict__ kk) {
  __shared__ float xs[32][129];
  __shared__ float wq[128][64];
  const int t = threadIdx.x;
  const int n0 = blockIdx.x * 32;
#pragma unroll
  for (int p = 0; p < 4; ++p) {
    int idx = t + p * 256;
    int row = idx >> 5, c4 = (idx & 31) * 4;
    const float4 v = *(const float4*)&x[(size_t)(n0 + row) * D_ + c4];
    xs[row][c4 + 0] = v.x; xs[row][c4 + 1] = v.y;
    xs[row][c4 + 2] = v.z; xs[row][c4 + 3] = v.w;
  }
#pragma unroll
  for (int p = 0; p < 8; ++p) {
    int idx = t + p * 256;
    int row = idx >> 4, c4 = (idx & 15) * 4;
    *(float4*)&wq[row][c4] = *(const float4*)&WQK[row * 64 + c4];
  }
  __syncthreads();
  const int node = t >> 3, cq = t & 7;
  float s[8];
#pragma unroll
  for (int j = 0; j < 8; ++j) s[j] = 0.f;
  for (int k = 0; k < 128; ++k) {
    float xv = xs[node][k];
#pragma unroll
    for (int j = 0; j < 8; ++j) s[j] = fmaf(xv, wq[k][cq * 8 + j], s[j]);
  }
#pragma unroll
  for (int j = 0; j < 8; ++j) {
    int c = cq * 8 + j;
    if (c < 32) q[(size_t)(n0 + node) * 32 + c] = s[j];
    else        kk[(size_t)(n0 + node) * 32 + (c - 32)] = s[j];
  }
}

// ---------------- fused attention softmax: wave per dst node, no atomics ----------------
__global__ __launch_bounds__(256) void k_attn(
    const int* __restrict__ ipN, const int* __restrict__ esD,
    const int* __restrict__ src, const int* __restrict__ et,
    const float* __restrict__ q, const float* __restrict__ kk,
    const int* __restrict__ slotOf, float* __restrict__ aw) {
  int n = blockIdx.x * 4 + (threadIdx.x >> 6);
  int lane = threadIdx.x & 63;
  int j0 = ipN[n], j1 = ipN[n + 1];
  int deg = j1 - j0;
  if (deg == 0) return;            // wave-uniform
  int h = lane & 3;
  int nch = (deg + 15) >> 4;
  float m = -3.4e38f;
  for (int c = 0; c < nch; ++c) {
    int ei = c * 16 + (lane >> 2);
    if (ei < deg) {
      int e = esD[j0 + ei];
      int r = et[e];
      float a = lrelu(q[(size_t)n * 32 + r * 4 + h] + kk[(size_t)src[e] * 32 + r * 4 + h]);
      m = fmaxf(m, a);
    }
  }
#pragma unroll
  for (int o = 4; o < 64; o <<= 1) m = fmaxf(m, __shfl_xor(m, o, 64));
  float s = 0.f;
  for (int c = 0; c < nch; ++c) {
    int ei = c * 16 + (lane >> 2);
    if (ei < deg) {
      int e = esD[j0 + ei];
      int r = et[e];
      float a = lrelu(q[(size_t)n * 32 + r * 4 + h] + kk[(size_t)src[e] * 32 + r * 4 + h]);
      float ex = expf(a - m);
      s += ex;
      aw[(size_t)slotOf[e] * 4 + h] = ex;
    }
  }
#pragma unroll
  for (int o = 4; o < 64; o <<= 1) s += __shfl_xor(s, o, 64);
  float inv = 0.25f / (s + 1e-16f);
  for (int c = 0; c < nch; ++c) {
    int ei = c * 16 + (lane >> 2);
    if (ei < deg) {
      int e = esD[j0 + ei];
      aw[(size_t)slotOf[e] * 4 + h] *= inv;
    }
  }
}

// W fp32 [L][R][D][HK] -> wt bf16 [L][R][HK][D]  (all layers, z = l*R+r)
__global__ void k_cvt_w_all(const float* __restrict__ W, u16* __restrict__ wt) {
  __shared__ u16 tile[64][65];
  const int z = blockIdx.z, k0 = blockIdx.y * 64, c0 = blockIdx.x * 64;
  const int t = threadIdx.x;
  const int tk = t >> 4, tc4 = (t & 15) * 4;
  const float* Wz = W + (size_t)z * D_ * HK_;
  u16* wz = wt + (size_t)z * HK_ * D_;
#pragma unroll
  for (int p = 0; p < 4; ++p) {
    int krow = tk + p * 16;
    const float4 v = *(const float4*)&Wz[(size_t)(k0 + krow) * HK_ + c0 + tc4];
    tile[tc4 + 0][krow] = bfr(v.x);
    tile[tc4 + 1][krow] = bfr(v.y);
    tile[tc4 + 2][krow] = bfr(v.z);
    tile[tc4 + 3][krow] = bfr(v.w);
  }
  __syncthreads();
#pragma unroll
  for (int p = 0; p < 4; ++p) {
    int crow = tk + p * 16;
    uint2 o;
    o.x = (u32)tile[crow][tc4 + 0] | ((u32)tile[crow][tc4 + 1] << 16);
    o.y = (u32)tile[crow][tc4 + 2] | ((u32)tile[crow][tc4 + 3] << 16);
    *(uint2*)&wz[(size_t)(c0 + crow) * D_ + k0 + tc4] = o;
  }
}

// ---------------- edge-GEMM v5: one 64-edge tile per block, massively parallel ----------------
// Grid 2568 blocks x 512 thr. B-frags from L2-hot Wtb (issued before meta barrier);
// A gathered to 16KB LDS; 64 MFMA/wave; in-register head-reduce epilogue.
// Latency hiding comes from 4+ co-resident blocks/CU, not intra-block pipelining.
__global__ __launch_bounds__(512) void k_edge5(
    const u16* __restrict__ xb, const u16* __restrict__ wt,   // wt: layer base [R][HK][D]
    const int* __restrict__ indptrR, const int* __restrict__ padBase,
    const int* __restrict__ srcR, const float* __restrict__ aw,
    u16* __restrict__ m) {
  __shared__ u16 atile[64 * 128];      // 16 KB, XOR-swizzled
  __shared__ float awl[64][4];
  __shared__ int srcl[64];
  const int t = threadIdx.x;
  const int b64 = blockIdx.x * 64;
  if (b64 >= padBase[R_]) return;      // block-uniform (few dead tail blocks)
  int r = 0;
  while (b64 >= padBase[r + 1]) ++r;   // block-uniform, <=8 iters
  const int ip0 = indptrR[r * N_];
  const int cnt = indptrR[(r + 1) * N_] - ip0;
  const int local0 = b64 - padBase[r];
  const u16* wrp = wt + (size_t)r * HK_ * D_;
  const int wid = t >> 6, lane = t & 63;
  const int l15 = lane & 15, l4 = lane >> 4;
  // B-frags from global (L2-hot), issued FIRST so latency overlaps meta+A-gather.
  // orig colfrag f = wid + 8h, c = f*16 + l15, elem k = ks*32 + l4*8
  short8 breg[4][4];                   // [ks][h]
#pragma unroll
  for (int ks = 0; ks < 4; ++ks)
#pragma unroll
    for (int h = 0; h < 4; ++h) {
      int c = (wid + 8 * h) * 16 + l15;
      breg[ks][h] = *(const short8*)(wrp + (size_t)c * 128 + ks * 32 + l4 * 8);
    }
  // meta (slots are rel-sorted: coalesced)
  if (t < 64) {
    int lidx = local0 + t;
    if (lidx < cnt) {
      srcl[t] = srcR[ip0 + lidx];
      *(float4*)awl[t] = *(const float4*)(aw + (size_t)(ip0 + lidx) * 4);
    } else {
      srcl[t] = 0;
      *(float4*)awl[t] = make_float4(0.f, 0.f, 0.f, 0.f);
    }
  }
  __syncthreads();   // meta visible
  // A gather -> LDS (2 uint4/thread; 16 lanes per row, coalesced 256B per row)
#pragma unroll
  for (int p = 0; p < 2; ++p) {
    int idx = t + p * 512;
    int row = idx >> 4, seg = idx & 15;
    uint4 v = *(const uint4*)(xb + (size_t)srcl[row] * 128 + seg * 8);
    *(uint4*)((char*)atile + row * 256 + ((seg * 16) ^ ((row & 7) << 4))) = v;
  }
  __syncthreads();   // A visible
  // MFMA: 64 rows x 16 out-cols (4 orig colfrags) x K=128 -> 64 MFMA, 16 ds_reads
  f32x4 acc[4][4];                     // [row i][h]
#pragma unroll
  for (int i = 0; i < 4; ++i)
#pragma unroll
    for (int h = 0; h < 4; ++h) acc[i][h] = (f32x4){0.f, 0.f, 0.f, 0.f};
#pragma unroll
  for (int ks = 0; ks < 4; ++ks) {
    short8 av[4];
#pragma unroll
    for (int i = 0; i < 4; ++i) {
      int row = i * 16 + l15;
      av[i] = *(const short8*)((char*)atile + row * 256 +
                ((l4 * 16 + ks * 64) ^ ((row & 7) << 4)));
    }
#pragma unroll
    for (int i = 0; i < 4; ++i)
#pragma unroll
      for (int h = 0; h < 4; ++h)
        // swapped operands: lane holds row = i*16+l15, cols (wid+8h)*16 + l4*4 + rg
        acc[i][h] = __builtin_amdgcn_mfma_f32_16x16x32_bf16(breg[ks][h], av[i],
                                                            acc[i][h], 0, 0, 0);
  }
  // epilogue: in-register head reduction -> out colfrag wid
#pragma unroll
  for (int i = 0; i < 4; ++i) {
    int row = i * 16 + l15;
    const float4 awf = *(const float4*)awl[row];
    float v0 = awf.x * acc[i][0][0] + awf.y * acc[i][1][0] + awf.z * acc[i][2][0] + awf.w * acc[i][3][0];
    float v1 = awf.x * acc[i][0][1] + awf.y * acc[i][1][1] + awf.z * acc[i][2][1] + awf.w * acc[i][3][1];
    float v2 = awf.x * acc[i][0][2] + awf.y * acc[i][1][2] + awf.z * acc[i][2][2] + awf.w * acc[i][3][2];
    float v3 = awf.x * acc[i][0][3] + awf.y * acc[i][1][3] + awf.z * acc[i][2][3] + awf.w * acc[i][3][3];
    uint2 o;
    o.x = (u32)bfr(v0) | ((u32)bfr(v1) << 16);
    o.y = (u32)bfr(v2) | ((u32)bfr(v3) << 16);
    *(uint2*)(m + (size_t)(b64 + row) * 128 + wid * 16 + l4 * 4) = o;
  }
}

// ---------------- aggregation + bias/relu + bf16-convert for next layer ----------------
__global__ __launch_bounds__(256) void k_agg2(
    const int* __restrict__ indptrR, const int* __restrict__ padBase,
    const u16* __restrict__ m, const float* __restrict__ Bl,
    float* __restrict__ xout, u16* __restrict__ xbout) {
  int n = blockIdx.x * 4 + (threadIdx.x >> 6);
  int lane = threadIdx.x & 63;
  float s0 = 0.f, s1 = 0.f;   // d = 2*lane, 2*lane+1
#pragma unroll
  for (int r = 0; r < R_; ++r) {
    int ip0 = indptrR[r * N_];
    int j0 = indptrR[r * N_ + n], j1 = indptrR[r * N_ + n + 1];
    int base = padBase[r] + (j0 - ip0);
    for (int j = 0; j < j1 - j0; ++j) {
      u32 v = *((const u32*)(m + (size_t)(base + j) * 128) + lane);
      s0 += bf2f(v & 0xffffu);
      s1 += bf2f(v >> 16);
    }
  }
  float2 o;
  o.x = fmaxf(s0 + Bl[2 * lane], 0.f);
  o.y = fmaxf(s1 + Bl[2 * lane + 1], 0.f);
  *((float2*)(xout + (size_t)n * D_) + lane) = o;
  ((u32*)(xbout + (size_t)n * D_))[lane] = (u32)bfr(o.x) | ((u32)bfr(o.y) << 16);
}

// ---------------- graph mean-pool ----------------
__global__ void k_pool(const float* __restrict__ x, float* __restrict__ pooled) {
  int i = blockIdx.x * blockDim.x + threadIdx.x; // G*D
  if (i >= G_ * D_) return;
  int d = i & 127, g = i >> 7;
  float s = 0.f;
  for (int j = 0; j < NPG_; ++j) s += x[(size_t)(g * NPG_ + j) * D_ + d];
  pooled[i] = s * (1.0f / NPG_);
}

// ---------------- head MLP ----------------
__global__ void k_head(const float* __restrict__ pooled, const float* __restrict__ fc1w,
                       const float* __restrict__ fc1b, const float* __restrict__ polw,
                       const float* __restrict__ polb, const float* __restrict__ valw,
                       const float* __restrict__ valb, float* __restrict__ out) {
  int g = blockIdx.x;
  int t = threadIdx.x; // 64
  __shared__ float hb[64];
  const float* p = pooled + (size_t)g * D_;
  float s = fc1b[t];
  for (int d = 0; d < D_; ++d) s += p[d] * fc1w[d * 64 + t];
  hb[t] = fmaxf(s, 0.f);
  __syncthreads();
  if (t < 7) {
    float s2 = polb[t];
    for (int j = 0; j < 64; ++j) s2 += hb[j] * polw[j * 7 + t];
    out[g * 7 + t] = s2;
  } else if (t == 7) {
    float s2 = valb[0];
    for (int j = 0; j < 64; ++j) s2 += hb[j] * valw[j];
    out[G_ * 7 + g] = tanhf(s2);
  }
}

extern "C" void kernel_launch(void* const* d_in, const int* in_sizes, int n_in,
                              void* d_out, int out_size, void* d_ws, size_t ws_size,
                              hipStream_t stream) {
  (void)in_sizes; (void)n_in; (void)out_size;
  const int*   x_nodes = (const int*)d_in[0];
  const int*   eidx    = (const int*)d_in[1];
  const int*   etype   = (const int*)d_in[2];
  const float* emb     = (const float*)d_in[4];
  const float* W       = (const float*)d_in[5];
  const float* Q       = (const float*)d_in[6];
  const float* Km      = (const float*)d_in[7];
  const float* B       = (const float*)d_in[8];
  const float* fc1w    = (const float*)d_in[9];
  const float* fc1b    = (const float*)d_in[10];
  const float* polw    = (const float*)d_in[11];
  const float* polb    = (const float*)d_in[12];
  const float* valw    = (const float*)d_in[13];
  const float* valb    = (const float*)d_in[14];
  float* out = (float*)d_out;
  const int* srcA = eidx;        // edge_index[0,:]
  const int* dstA = eidx + E_;   // edge_index[1,:]

  char* p = (char*)d_ws;
  size_t used = 0;
  auto carve = [&](size_t bytes) {
    char* q = p;
    size_t adv = (bytes + 255) & ~(size_t)255;
    p += adv;
    used += adv;
    return q;
  };
  float* x_cur  = (float*)carve((size_t)N_ * D_ * 4);            // 10.5 MB
  float* x_nxt  = (float*)carve((size_t)N_ * D_ * 4);            // 10.5 MB
  u16*   xbf    = (u16*)carve((size_t)N_ * D_ * 2);              // 5.2 MB
  u16*   mbuf   = (u16*)carve((size_t)(E_ + 512) * D_ * 2);      // 42.1 MB
  float* qbuf   = (float*)carve((size_t)N_ * 32 * 4);            // 2.6 MB
  float* kbuf   = (float*)carve((size_t)N_ * 32 * 4);            // 2.6 MB
  float* awbuf  = (float*)carve((size_t)E_ * H_ * 4);            // 2.6 MB
  float* WQKb   = (float*)carve((size_t)L_ * D_ * 64 * 4);       // 131 KB
  u16*   Wtb    = (u16*)carve((size_t)L_ * R_ * HK_ * D_ * 2);   // 4.2 MB
  float* pooled = (float*)carve((size_t)G_ * D_ * 4);
  int* countsR  = (int*)carve((size_t)R_ * N_ * 4);
  int* cursorR  = (int*)carve((size_t)R_ * N_ * 4);
  int* indptrR  = (int*)carve((size_t)(R_ * N_ + 1) * 4);
  int* esortR   = (int*)carve((size_t)E_ * 4);
  int* slotOf   = (int*)carve((size_t)E_ * 4);
  int* srcR     = (int*)carve((size_t)E_ * 4);
  int* countsN  = (int*)carve((size_t)N_ * 4);
  int* cursorN  = (int*)carve((size_t)N_ * 4);
  int* indptrN  = (int*)carve((size_t)(N_ + 1) * 4);
  int* esortD   = (int*)carve((size_t)E_ * 4);
  int* padBase  = (int*)carve((size_t)(R_ + 1) * 4);
  int* bsum     = (int*)carve((size_t)512 * 4);
  if (used > ws_size) return;  // defensive: fail via poisoned output, not OOB crash

  constexpr int RN = R_ * N_;          // 163840
  constexpr int NBR = RN / 1024;       // 160
  constexpr int NBN = N_ / 1024;       // 20
  constexpr int EDGE_BLOCKS = E_ / 64 + R_;  // 2568 (covers padding)

  // ---- rel-CSR + dst-CSR build + one-time precomputes ----
  k_zero_i<<<(RN + 255) / 256, 256, 0, stream>>>(countsR, RN);
  k_zero_i<<<(N_ + 255) / 256, 256, 0, stream>>>(countsN, N_);
  k_count_rel<<<E_ / 256, 256, 0, stream>>>(dstA, etype, countsR);
  k_count_dst<<<E_ / 256, 256, 0, stream>>>(dstA, countsN);
  k_bsum<<<NBR, 256, 0, stream>>>(countsR, bsum);
  k_bscan<<<1, 512, 0, stream>>>(bsum, NBR, indptrR + RN);  // writes indptrR[RN]=E
  k_scan3<<<NBR, 256, 0, stream>>>(countsR, bsum, indptrR, cursorR);
  k_scatter_rel<<<E_ / 256, 256, 0, stream>>>(dstA, etype, srcA, cursorR, esortR,
                                              slotOf, srcR);
  k_bsum<<<NBN, 256, 0, stream>>>(countsN, bsum);
  k_bscan<<<1, 512, 0, stream>>>(bsum, NBN, indptrN + N_);
  k_scan3<<<NBN, 256, 0, stream>>>(countsN, bsum, indptrN, cursorN);
  k_scatter_dst<<<E_ / 256, 256, 0, stream>>>(dstA, cursorN, esortD);
  k_padbase<<<1, 64, 0, stream>>>(indptrR, padBase);
  k_embed<<<(N_ * D_) / 256, 256, 0, stream>>>(x_nodes, emb, x_cur, xbf);
  k_wqk_all<<<(L_ * R_ * D_ * 64) / 256, 256, 0, stream>>>(W, Q, Km, WQKb);
  k_cvt_w_all<<<dim3(HK_ / 64, D_ / 64, L_ * R_), 256, 0, stream>>>(W, Wtb);

  for (int l = 0; l < L_; ++l) {
    const float* Bl = B + (size_t)l * D_;
    k_qk<<<N_ / 32, 256, 0, stream>>>(x_cur, WQKb + (size_t)l * D_ * 64, qbuf, kbuf);
    k_attn<<<N_ / 4, 256, 0, stream>>>(indptrN, esortD, srcA, etype, qbuf, kbuf,
                                       slotOf, awbuf);
    k_edge5<<<EDGE_BLOCKS, 512, 0, stream>>>(xbf, Wtb + (size_t)l * R_ * HK_ * D_,
                                             indptrR, padBase, srcR, awbuf, mbuf);
    k_agg2<<<N_ / 4, 256, 0, stream>>>(indptrR, padBase, mbuf, Bl, x_nxt, xbf);
    float* tmp = x_cur; x_cur = x_nxt; x_nxt = tmp;
  }

  k_pool<<<(G_ * D_) / 256, 256, 0, stream>>>(x_cur, pooled);
  k_head<<<G_, 64, 0, stream>>>(pooled, fc1w, fc1b, polw, polb, valw, valb, out);
}

// Round 12
// 522.510 us; speedup vs baseline: 1.0413x; 1.0413x over previous
//
#include <hip/hip_runtime.h>
#include <cstdint>
#include <cstddef>

constexpr int N_  = 20480;
constexpr int E_  = 163840;
constexpr int G_  = 512;
constexpr int D_  = 128;
constexpr int H_  = 4;
constexpr int R_  = 8;
constexpr int L_  = 4;
constexpr int HK_ = 512;   // H*D
constexpr int NPG_ = N_ / G_; // 40

typedef short short8 __attribute__((ext_vector_type(8)));
typedef float f32x4 __attribute__((ext_vector_type(4)));
typedef unsigned short u16;
typedef unsigned int u32;

__device__ inline u16 bfr(float f) {  // fp32 -> bf16 RNE
  u32 u = __builtin_bit_cast(u32, f);
  return (u16)((u + 0x7fffu + ((u >> 16) & 1u)) >> 16);
}
__device__ inline float bf2f(u32 lo16) { return __builtin_bit_cast(float, lo16 << 16); }
__device__ inline float lrelu(float v) { return v >= 0.f ? v : 0.2f * v; }

// ---------------- zero helper ----------------
__global__ void k_zero_i(int* __restrict__ p, int n) {
  int i = blockIdx.x * blockDim.x + threadIdx.x;
  if (i < n) p[i] = 0;
}

// ---------------- CSR builds ----------------
__global__ void k_count_rel(const int* __restrict__ dst, const int* __restrict__ et,
                            int* __restrict__ counts) {
  int e = blockIdx.x * blockDim.x + threadIdx.x;
  if (e < E_) atomicAdd(&counts[et[e] * N_ + dst[e]], 1);
}
__global__ void k_count_dst(const int* __restrict__ dst, int* __restrict__ counts) {
  int e = blockIdx.x * blockDim.x + threadIdx.x;
  if (e < E_) atomicAdd(&counts[dst[e]], 1);
}
__global__ void k_bsum(const int* __restrict__ c, int* __restrict__ bsum) {
  int t = threadIdx.x;
  const int4 v = *(const int4*)&c[blockIdx.x * 1024 + t * 4];
  int s = v.x + v.y + v.z + v.w;
#pragma unroll
  for (int o = 32; o; o >>= 1) s += __shfl_down(s, o, 64);
  __shared__ int ws_[4];
  if ((t & 63) == 0) ws_[t >> 6] = s;
  __syncthreads();
  if (t == 0) bsum[blockIdx.x] = ws_[0] + ws_[1] + ws_[2] + ws_[3];
}
// writes grand total too (r6 lesson: indptr[last] MUST be initialized)
__global__ void k_bscan(int* __restrict__ bsum, int nb, int* __restrict__ tot_out) {
  __shared__ int sh[512];
  int t = threadIdx.x;
  if (t < nb) sh[t] = bsum[t];
  __syncthreads();
  if (t == 0) {
    int run = 0;
    for (int i = 0; i < nb; ++i) { int v = sh[i]; sh[i] = run; run += v; }
    tot_out[0] = run;
  }
  __syncthreads();
  if (t < nb) bsum[t] = sh[t];
}
__global__ void k_scan3(const int* __restrict__ c, const int* __restrict__ bsum,
                        int* __restrict__ indptr, int* __restrict__ cursor) {
  __shared__ int ts[256];
  int t = threadIdx.x;
  int base = blockIdx.x * 1024 + t * 4;
  const int4 v = *(const int4*)&c[base];
  int s0 = v.x, s01 = v.x + v.y, s012 = s01 + v.z, s = s012 + v.w;
  ts[t] = s;
  __syncthreads();
#pragma unroll
  for (int o = 1; o < 256; o <<= 1) {
    int add = (t >= o) ? ts[t - o] : 0;
    __syncthreads();
    ts[t] += add;
    __syncthreads();
  }
  int off = bsum[blockIdx.x] + (t ? ts[t - 1] : 0);
  int4 o4 = make_int4(off, off + s0, off + s01, off + s012);
  *(int4*)&indptr[base] = o4;
  *(int4*)&cursor[base] = o4;
}
// rel scatter; also records slotOf[e] and srcR[slot] (static per session)
__global__ void k_scatter_rel(const int* __restrict__ dst, const int* __restrict__ et,
                              const int* __restrict__ src, int* __restrict__ cursor,
                              int* __restrict__ esort, int* __restrict__ slotOf,
                              int* __restrict__ srcR) {
  int e = blockIdx.x * blockDim.x + threadIdx.x;
  if (e < E_) {
    int p = atomicAdd(&cursor[et[e] * N_ + dst[e]], 1);
    esort[p] = e;
    slotOf[e] = p;
    srcR[p] = src[e];
  }
}
__global__ void k_scatter_dst(const int* __restrict__ dst, int* __restrict__ cursor,
                              int* __restrict__ esort) {
  int e = blockIdx.x * blockDim.x + threadIdx.x;
  if (e < E_) {
    int p = atomicAdd(&cursor[dst[e]], 1);
    esort[p] = e;
  }
}
__global__ void k_padbase(const int* __restrict__ indptrR, int* __restrict__ padBase) {
  if (threadIdx.x == 0 && blockIdx.x == 0) {
    int cum = 0;
    for (int r = 0; r < R_; ++r) {
      padBase[r] = cum;
      int cnt = indptrR[(r + 1) * N_] - indptrR[r * N_];
      cum += (cnt + 63) & ~63;
    }
    padBase[R_] = cum;
  }
}

// ---------------- embedding lookup (writes fp32 + bf16) ----------------
__global__ void k_embed(const int* __restrict__ xn, const float* __restrict__ emb,
                        float* __restrict__ x, u16* __restrict__ xb) {
  int i = blockIdx.x * blockDim.x + threadIdx.x;
  if (i < N_ * D_) {
    int n = i >> 7, d = i & 127;
    float v = emb[xn[n] * D_ + d];
    x[i] = v;
    xb[i] = bfr(v);
  }
}

// ---------------- WQK for ALL layers: wave per (l,r,d) row ----------------
__global__ __launch_bounds__(256) void k_wqk_all(const float* __restrict__ W,
                                                 const float* __restrict__ Q,
                                                 const float* __restrict__ Km,
                                                 float* __restrict__ WQK) {
  int gw = (blockIdx.x * 256 + threadIdx.x) >> 6;  // 0..L*R*D-1 = 4095
  int lane = threadIdx.x & 63;
  int d = gw & 127, r = (gw >> 7) & 7, l = gw >> 10;
  const float* wrow = W + (((size_t)l * R_ + r) * D_ + d) * HK_;
  const float* Ql = Q + (size_t)l * HK_ * H_;
  const float* Kl = Km + (size_t)l * HK_ * H_;
  float acc[8] = {0.f, 0.f, 0.f, 0.f, 0.f, 0.f, 0.f, 0.f};
#pragma unroll
  for (int it = 0; it < 8; ++it) {
    int k = it * 64 + lane;
    float w = wrow[k];
    const float4 qv = *(const float4*)&Ql[k * 4];
    const float4 kv = *(const float4*)&Kl[k * 4];
    acc[0] += w * qv.x; acc[1] += w * qv.y; acc[2] += w * qv.z; acc[3] += w * qv.w;
    acc[4] += w * kv.x; acc[5] += w * kv.y; acc[6] += w * kv.z; acc[7] += w * kv.w;
  }
#pragma unroll
  for (int o = 32; o; o >>= 1)
#pragma unroll
    for (int j = 0; j < 8; ++j) acc[j] += __shfl_down(acc[j], o, 64);
  if (lane == 0) {
#pragma unroll
    for (int h = 0; h < 4; ++h) {
      WQK[((size_t)l * D_ + d) * 64 + r * 4 + h] = acc[h];
      WQK[((size_t)l * D_ + d) * 64 + 32 + r * 4 + h] = acc[4 + h];
    }
  }
}

// ---------------- q,k: LDS-tiled small GEMM (32 nodes/block) ----------------
__global__ __launch_bounds__(256) void k_qk(const float* __restrict__ x,
                                            const float* __restrict__ WQK,
                                            float* __restrict__ q,
                                            float* __restrict__ kk) {
  __shared__ float xs[32][129];
  __shared__ float wq[128][64];
  const int t = threadIdx.x;
  const int n0 = blockIdx.x * 32;
#pragma unroll
  for (int p = 0; p < 4; ++p) {
    int idx = t + p * 256;
    int row = idx >> 5, c4 = (idx & 31) * 4;
    const float4 v = *(const float4*)&x[(size_t)(n0 + row) * D_ + c4];
    xs[row][c4 + 0] = v.x; xs[row][c4 + 1] = v.y;
    xs[row][c4 + 2] = v.z; xs[row][c4 + 3] = v.w;
  }
#pragma unroll
  for (int p = 0; p < 8; ++p) {
    int idx = t + p * 256;
    int row = idx >> 4, c4 = (idx & 15) * 4;
    *(float4*)&wq[row][c4] = *(const float4*)&WQK[row * 64 + c4];
  }
  __syncthreads();
  const int node = t >> 3, cq = t & 7;
  float s[8];
#pragma unroll
  for (int j = 0; j < 8; ++j) s[j] = 0.f;
  for (int k = 0; k < 128; ++k) {
    float xv = xs[node][k];
#pragma unroll
    for (int j = 0; j < 8; ++j) s[j] = fmaf(xv, wq[k][cq * 8 + j], s[j]);
  }
#pragma unroll
  for (int j = 0; j < 8; ++j) {
    int c = cq * 8 + j;
    if (c < 32) q[(size_t)(n0 + node) * 32 + c] = s[j];
    else        kk[(size_t)(n0 + node) * 32 + (c - 32)] = s[j];
  }
}

// ---------------- fused attention softmax: wave per dst node, no atomics ----------------
__global__ __launch_bounds__(256) void k_attn(
    const int* __restrict__ ipN, const int* __restrict__ esD,
    const int* __restrict__ src, const int* __restrict__ et,
    const float* __restrict__ q, const float* __restrict__ kk,
    const int* __restrict__ slotOf, float* __restrict__ aw) {
  int n = blockIdx.x * 4 + (threadIdx.x >> 6);
  int lane = threadIdx.x & 63;
  int j0 = ipN[n], j1 = ipN[n + 1];
  int deg = j1 - j0;
  if (deg == 0) return;            // wave-uniform
  int h = lane & 3;
  int nch = (deg + 15) >> 4;
  float m = -3.4e38f;
  for (int c = 0; c < nch; ++c) {
    int ei = c * 16 + (lane >> 2);
    if (ei < deg) {
      int e = esD[j0 + ei];
      int r = et[e];
      float a = lrelu(q[(size_t)n * 32 + r * 4 + h] + kk[(size_t)src[e] * 32 + r * 4 + h]);
      m = fmaxf(m, a);
    }
  }
#pragma unroll
  for (int o = 4; o < 64; o <<= 1) m = fmaxf(m, __shfl_xor(m, o, 64));
  float s = 0.f;
  for (int c = 0; c < nch; ++c) {
    int ei = c * 16 + (lane >> 2);
    if (ei < deg) {
      int e = esD[j0 + ei];
      int r = et[e];
      float a = lrelu(q[(size_t)n * 32 + r * 4 + h] + kk[(size_t)src[e] * 32 + r * 4 + h]);
      float ex = expf(a - m);
      s += ex;
      aw[(size_t)slotOf[e] * 4 + h] = ex;
    }
  }
#pragma unroll
  for (int o = 4; o < 64; o <<= 1) s += __shfl_xor(s, o, 64);
  float inv = 0.25f / (s + 1e-16f);
  for (int c = 0; c < nch; ++c) {
    int ei = c * 16 + (lane >> 2);
    if (ei < deg) {
      int e = esD[j0 + ei];
      aw[(size_t)slotOf[e] * 4 + h] *= inv;
    }
  }
}

// W fp32 [L][R][D][HK] -> wt bf16 [L][R][HK][D]  (all layers, z = l*R+r)
__global__ void k_cvt_w_all(const float* __restrict__ W, u16* __restrict__ wt) {
  __shared__ u16 tile[64][65];
  const int z = blockIdx.z, k0 = blockIdx.y * 64, c0 = blockIdx.x * 64;
  const int t = threadIdx.x;
  const int tk = t >> 4, tc4 = (t & 15) * 4;
  const float* Wz = W + (size_t)z * D_ * HK_;
  u16* wz = wt + (size_t)z * HK_ * D_;
#pragma unroll
  for (int p = 0; p < 4; ++p) {
    int krow = tk + p * 16;
    const float4 v = *(const float4*)&Wz[(size_t)(k0 + krow) * HK_ + c0 + tc4];
    tile[tc4 + 0][krow] = bfr(v.x);
    tile[tc4 + 1][krow] = bfr(v.y);
    tile[tc4 + 2][krow] = bfr(v.z);
    tile[tc4 + 3][krow] = bfr(v.w);
  }
  __syncthreads();
#pragma unroll
  for (int p = 0; p < 4; ++p) {
    int crow = tk + p * 16;
    uint2 o;
    o.x = (u32)tile[crow][tc4 + 0] | ((u32)tile[crow][tc4 + 1] << 16);
    o.y = (u32)tile[crow][tc4 + 2] | ((u32)tile[crow][tc4 + 3] << 16);
    *(uint2*)&wz[(size_t)(c0 + crow) * D_ + k0 + tc4] = o;
  }
}

// ---------------- edge-GEMM v6: persistent, B pinned in VGPRs via inline-asm loads ----------------
// Grid: 8 relations x 32 sub-blocks, 512 threads. Each wave owns ONE output colfrag.
// The 16 B-frag loads are inline asm -> compiler CANNOT rematerialize them; they
// stay resident (64 VGPR) across the whole tile loop. Per tile: 16 ds_reads + 64 MFMA.
__global__ __launch_bounds__(512, 1) void k_edge6(
    const u16* __restrict__ xb, const u16* __restrict__ wt,   // wt: layer base [R][HK][D]
    const int* __restrict__ indptrR, const int* __restrict__ padBase,
    const int* __restrict__ srcR, const float* __restrict__ aw,
    u16* __restrict__ m) {
  __shared__ u16 atile[64 * 128];      // 16 KB, XOR-swizzled
  __shared__ float awl[2][64][4];      // 2 KB (double-buffered meta)
  __shared__ int srcl[2][64];
  const int t = threadIdx.x;
  const int r = blockIdx.x >> 5;
  const int sub = blockIdx.x & 31;
  const int ip0 = indptrR[r * N_];
  const int cnt = indptrR[(r + 1) * N_] - ip0;
  const int nt = (cnt + 63) >> 6;      // tiles for this relation
  const int pb = padBase[r];           // padded slot base (edge units)
  const u16* wrp = wt + (size_t)r * HK_ * D_;
  const int wid = t >> 6, lane = t & 63;
  const int l15 = lane & 15, l4 = lane >> 4;
  // B-frags: orig colfrag f = wid + 8h, c = f*16 + l15, elems k = ks*32 + l4*8 ..+7
  // Loaded via inline asm so the values are opaque to the register allocator ->
  // no remat, guaranteed resident.
  uint4 breg[4][4];                    // [ks][h] = 64 VGPR
#pragma unroll
  for (int ks = 0; ks < 4; ++ks)
#pragma unroll
    for (int h = 0; h < 4; ++h) {
      const u16* ap = wrp + (size_t)((wid + 8 * h) * 16 + l15) * 128 + ks * 32 + l4 * 8;
      asm volatile("global_load_dwordx4 %0, %1, off" : "=v"(breg[ks][h]) : "v"(ap));
    }
  // meta for first tile -> buf 0
  if (sub < nt && t < 64) {
    int lidx = sub * 64 + t;
    if (lidx < cnt) {
      srcl[0][t] = srcR[ip0 + lidx];
      *(float4*)awl[0][t] = *(const float4*)(aw + (size_t)(ip0 + lidx) * 4);
    } else {
      srcl[0][t] = 0;
      *(float4*)awl[0][t] = make_float4(0.f, 0.f, 0.f, 0.f);
    }
  }
  __syncthreads();   // meta0 visible
  // drain asm loads (HW counter; compiler doesn't track them) + pin ordering
  asm volatile("s_waitcnt vmcnt(0)" ::: "memory");
  __builtin_amdgcn_sched_barrier(0);
  // A prefetch for first tile (2 uint4/thread, 512 threads -> 64 x 256B rows)
  uint4 pa[2];
  if (sub < nt) {
#pragma unroll
    for (int p = 0; p < 2; ++p) {
      int idx = t + p * 512;
      pa[p] = *(const uint4*)(xb + (size_t)srcl[0][idx >> 4] * 128 + (idx & 15) * 8);
    }
  }
  int cur = 0;
  for (int tile = sub; tile < nt; tile += 32) {
    const int nxt = cur ^ 1;
    const int ntile = tile + 32;
    // write prefetched A regs to LDS
#pragma unroll
    for (int p = 0; p < 2; ++p) {
      int idx = t + p * 512;
      int row = idx >> 4, seg = idx & 15;
      *(uint4*)((char*)atile + row * 256 + ((seg * 16) ^ ((row & 7) << 4))) = pa[p];
    }
    // meta(next tile) coalesced loads
    if (ntile < nt && t < 64) {
      int lidx = ntile * 64 + t;
      if (lidx < cnt) {
        srcl[nxt][t] = srcR[ip0 + lidx];
        *(float4*)awl[nxt][t] = *(const float4*)(aw + (size_t)(ip0 + lidx) * 4);
      } else {
        srcl[nxt][t] = 0;
        *(float4*)awl[nxt][t] = make_float4(0.f, 0.f, 0.f, 0.f);
      }
    }
    __syncthreads();   // A + meta(next) visible
    // issue A prefetch for next tile (hides under MFMA)
    if (ntile < nt) {
#pragma unroll
      for (int p = 0; p < 2; ++p) {
        int idx = t + p * 512;
        pa[p] = *(const uint4*)(xb + (size_t)srcl[nxt][idx >> 4] * 128 + (idx & 15) * 8);
      }
    }
    // MFMA: 64 rows x 16 out-cols (4 orig colfrags) x K=128 -> 64 MFMA, 16 ds_reads
    f32x4 acc[4][4];                   // [row i][h]
#pragma unroll
    for (int i = 0; i < 4; ++i)
#pragma unroll
      for (int h = 0; h < 4; ++h) acc[i][h] = (f32x4){0.f, 0.f, 0.f, 0.f};
#pragma unroll
    for (int ks = 0; ks < 4; ++ks) {
      short8 av[4];
#pragma unroll
      for (int i = 0; i < 4; ++i) {
        int row = i * 16 + l15;
        av[i] = *(const short8*)((char*)atile + row * 256 +
                  ((l4 * 16 + ks * 64) ^ ((row & 7) << 4)));
      }
#pragma unroll
      for (int i = 0; i < 4; ++i)
#pragma unroll
        for (int h = 0; h < 4; ++h)
          // swapped operands: lane holds row = i*16+l15, cols (wid+8h)*16 + l4*4 + rg
          acc[i][h] = __builtin_amdgcn_mfma_f32_16x16x32_bf16(
              __builtin_bit_cast(short8, breg[ks][h]), av[i], acc[i][h], 0, 0, 0);
    }
    // epilogue: in-register head reduction -> out colfrag wid
#pragma unroll
    for (int i = 0; i < 4; ++i) {
      int row = i * 16 + l15;
      const float4 awf = *(const float4*)awl[cur][row];
      float v0 = awf.x * acc[i][0][0] + awf.y * acc[i][1][0] + awf.z * acc[i][2][0] + awf.w * acc[i][3][0];
      float v1 = awf.x * acc[i][0][1] + awf.y * acc[i][1][1] + awf.z * acc[i][2][1] + awf.w * acc[i][3][1];
      float v2 = awf.x * acc[i][0][2] + awf.y * acc[i][1][2] + awf.z * acc[i][2][2] + awf.w * acc[i][3][2];
      float v3 = awf.x * acc[i][0][3] + awf.y * acc[i][1][3] + awf.z * acc[i][2][3] + awf.w * acc[i][3][3];
      uint2 o;
      o.x = (u32)bfr(v0) | ((u32)bfr(v1) << 16);
      o.y = (u32)bfr(v2) | ((u32)bfr(v3) << 16);
      *(uint2*)(m + (size_t)(pb + tile * 64 + row) * 128 + wid * 16 + l4 * 4) = o;
    }
    __syncthreads();   // all waves done with atile + awl[cur] before overwrite
    cur = nxt;
  }
}

// ---------------- aggregation + bias/relu + bf16-convert for next layer ----------------
__global__ __launch_bounds__(256) void k_agg2(
    const int* __restrict__ indptrR, const int* __restrict__ padBase,
    const u16* __restrict__ m, const float* __restrict__ Bl,
    float* __restrict__ xout, u16* __restrict__ xbout) {
  int n = blockIdx.x * 4 + (threadIdx.x >> 6);
  int lane = threadIdx.x & 63;
  float s0 = 0.f, s1 = 0.f;   // d = 2*lane, 2*lane+1
#pragma unroll
  for (int r = 0; r < R_; ++r) {
    int ip0 = indptrR[r * N_];
    int j0 = indptrR[r * N_ + n], j1 = indptrR[r * N_ + n + 1];
    int base = padBase[r] + (j0 - ip0);
    for (int j = 0; j < j1 - j0; ++j) {
      u32 v = *((const u32*)(m + (size_t)(base + j) * 128) + lane);
      s0 += bf2f(v & 0xffffu);
      s1 += bf2f(v >> 16);
    }
  }
  float2 o;
  o.x = fmaxf(s0 + Bl[2 * lane], 0.f);
  o.y = fmaxf(s1 + Bl[2 * lane + 1], 0.f);
  *((float2*)(xout + (size_t)n * D_) + lane) = o;
  ((u32*)(xbout + (size_t)n * D_))[lane] = (u32)bfr(o.x) | ((u32)bfr(o.y) << 16);
}

// ---------------- graph mean-pool ----------------
__global__ void k_pool(const float* __restrict__ x, float* __restrict__ pooled) {
  int i = blockIdx.x * blockDim.x + threadIdx.x; // G*D
  if (i >= G_ * D_) return;
  int d = i & 127, g = i >> 7;
  float s = 0.f;
  for (int j = 0; j < NPG_; ++j) s += x[(size_t)(g * NPG_ + j) * D_ + d];
  pooled[i] = s * (1.0f / NPG_);
}

// ---------------- head MLP ----------------
__global__ void k_head(const float* __restrict__ pooled, const float* __restrict__ fc1w,
                       const float* __restrict__ fc1b, const float* __restrict__ polw,
                       const float* __restrict__ polb, const float* __restrict__ valw,
                       const float* __restrict__ valb, float* __restrict__ out) {
  int g = blockIdx.x;
  int t = threadIdx.x; // 64
  __shared__ float hb[64];
  const float* p = pooled + (size_t)g * D_;
  float s = fc1b[t];
  for (int d = 0; d < D_; ++d) s += p[d] * fc1w[d * 64 + t];
  hb[t] = fmaxf(s, 0.f);
  __syncthreads();
  if (t < 7) {
    float s2 = polb[t];
    for (int j = 0; j < 64; ++j) s2 += hb[j] * polw[j * 7 + t];
    out[g * 7 + t] = s2;
  } else if (t == 7) {
    float s2 = valb[0];
    for (int j = 0; j < 64; ++j) s2 += hb[j] * valw[j];
    out[G_ * 7 + g] = tanhf(s2);
  }
}

extern "C" void kernel_launch(void* const* d_in, const int* in_sizes, int n_in,
                              void* d_out, int out_size, void* d_ws, size_t ws_size,
                              hipStream_t stream) {
  (void)in_sizes; (void)n_in; (void)out_size;
  const int*   x_nodes = (const int*)d_in[0];
  const int*   eidx    = (const int*)d_in[1];
  const int*   etype   = (const int*)d_in[2];
  const float* emb     = (const float*)d_in[4];
  const float* W       = (const float*)d_in[5];
  const float* Q       = (const float*)d_in[6];
  const float* Km      = (const float*)d_in[7];
  const float* B       = (const float*)d_in[8];
  const float* fc1w    = (const float*)d_in[9];
  const float* fc1b    = (const float*)d_in[10];
  const float* polw    = (const float*)d_in[11];
  const float* polb    = (const float*)d_in[12];
  const float* valw    = (const float*)d_in[13];
  const float* valb    = (const float*)d_in[14];
  float* out = (float*)d_out;
  const int* srcA = eidx;        // edge_index[0,:]
  const int* dstA = eidx + E_;   // edge_index[1,:]

  char* p = (char*)d_ws;
  size_t used = 0;
  auto carve = [&](size_t bytes) {
    char* q = p;
    size_t adv = (bytes + 255) & ~(size_t)255;
    p += adv;
    used += adv;
    return q;
  };
  float* x_cur  = (float*)carve((size_t)N_ * D_ * 4);            // 10.5 MB
  float* x_nxt  = (float*)carve((size_t)N_ * D_ * 4);            // 10.5 MB
  u16*   xbf    = (u16*)carve((size_t)N_ * D_ * 2);              // 5.2 MB
  u16*   mbuf   = (u16*)carve((size_t)(E_ + 512) * D_ * 2);      // 42.1 MB
  float* qbuf   = (float*)carve((size_t)N_ * 32 * 4);            // 2.6 MB
  float* kbuf   = (float*)carve((size_t)N_ * 32 * 4);            // 2.6 MB
  float* awbuf  = (float*)carve((size_t)E_ * H_ * 4);            // 2.6 MB
  float* WQKb   = (float*)carve((size_t)L_ * D_ * 64 * 4);       // 131 KB
  u16*   Wtb    = (u16*)carve((size_t)L_ * R_ * HK_ * D_ * 2);   // 4.2 MB
  float* pooled = (float*)carve((size_t)G_ * D_ * 4);
  int* countsR  = (int*)carve((size_t)R_ * N_ * 4);
  int* cursorR  = (int*)carve((size_t)R_ * N_ * 4);
  int* indptrR  = (int*)carve((size_t)(R_ * N_ + 1) * 4);
  int* esortR   = (int*)carve((size_t)E_ * 4);
  int* slotOf   = (int*)carve((size_t)E_ * 4);
  int* srcR     = (int*)carve((size_t)E_ * 4);
  int* countsN  = (int*)carve((size_t)N_ * 4);
  int* cursorN  = (int*)carve((size_t)N_ * 4);
  int* indptrN  = (int*)carve((size_t)(N_ + 1) * 4);
  int* esortD   = (int*)carve((size_t)E_ * 4);
  int* padBase  = (int*)carve((size_t)(R_ + 1) * 4);
  int* bsum     = (int*)carve((size_t)512 * 4);
  if (used > ws_size) return;  // defensive: fail via poisoned output, not OOB crash

  constexpr int RN = R_ * N_;          // 163840
  constexpr int NBR = RN / 1024;       // 160
  constexpr int NBN = N_ / 1024;       // 20

  // ---- rel-CSR + dst-CSR build + one-time precomputes ----
  k_zero_i<<<(RN + 255) / 256, 256, 0, stream>>>(countsR, RN);
  k_zero_i<<<(N_ + 255) / 256, 256, 0, stream>>>(countsN, N_);
  k_count_rel<<<E_ / 256, 256, 0, stream>>>(dstA, etype, countsR);
  k_count_dst<<<E_ / 256, 256, 0, stream>>>(dstA, countsN);
  k_bsum<<<NBR, 256, 0, stream>>>(countsR, bsum);
  k_bscan<<<1, 512, 0, stream>>>(bsum, NBR, indptrR + RN);  // writes indptrR[RN]=E
  k_scan3<<<NBR, 256, 0, stream>>>(countsR, bsum, indptrR, cursorR);
  k_scatter_rel<<<E_ / 256, 256, 0, stream>>>(dstA, etype, srcA, cursorR, esortR,
                                              slotOf, srcR);
  k_bsum<<<NBN, 256, 0, stream>>>(countsN, bsum);
  k_bscan<<<1, 512, 0, stream>>>(bsum, NBN, indptrN + N_);
  k_scan3<<<NBN, 256, 0, stream>>>(countsN, bsum, indptrN, cursorN);
  k_scatter_dst<<<E_ / 256, 256, 0, stream>>>(dstA, cursorN, esortD);
  k_padbase<<<1, 64, 0, stream>>>(indptrR, padBase);
  k_embed<<<(N_ * D_) / 256, 256, 0, stream>>>(x_nodes, emb, x_cur, xbf);
  k_wqk_all<<<(L_ * R_ * D_ * 64) / 256, 256, 0, stream>>>(W, Q, Km, WQKb);
  k_cvt_w_all<<<dim3(HK_ / 64, D_ / 64, L_ * R_), 256, 0, stream>>>(W, Wtb);

  for (int l = 0; l < L_; ++l) {
    const float* Bl = B + (size_t)l * D_;
    k_qk<<<N_ / 32, 256, 0, stream>>>(x_cur, WQKb + (size_t)l * D_ * 64, qbuf, kbuf);
    k_attn<<<N_ / 4, 256, 0, stream>>>(indptrN, esortD, srcA, etype, qbuf, kbuf,
                                       slotOf, awbuf);
    k_edge6<<<R_ * 32, 512, 0, stream>>>(xbf, Wtb + (size_t)l * R_ * HK_ * D_,
                                         indptrR, padBase, srcR, awbuf, mbuf);
    k_agg2<<<N_ / 4, 256, 0, stream>>>(indptrR, padBase, mbuf, Bl, x_nxt, xbf);
    float* tmp = x_cur; x_cur = x_nxt; x_nxt = tmp;
  }

  k_pool<<<(G_ * D_) / 256, 256, 0, stream>>>(x_cur, pooled);
  k_head<<<G_, 64, 0, stream>>>(pooled, fc1w, fc1b, polw, polb, valw, valb, out);
}